// Round 8
// baseline (938.432 us; speedup 1.0000x reference)
//
#include <hip/hip_runtime.h>

typedef __attribute__((ext_vector_type(8))) short short8;
typedef __attribute__((ext_vector_type(4))) float f32x4;
typedef __attribute__((ext_vector_type(4))) unsigned uint4v;   // native vector for nontemporal builtins

// ---------------- bf16 helpers ----------------
__device__ inline unsigned f2bf(float f) {
    unsigned u = __float_as_uint(f);
    u += 0x7fffu + ((u >> 16) & 1u);   // round-to-nearest-even
    return u >> 16;
}
__device__ inline float bf2f(ushort h) { return __uint_as_float(((unsigned)h) << 16); }

// ---------------- CSR build ----------------

__global__ __launch_bounds__(256) void k_count(const int* __restrict__ ei, int* __restrict__ cnt, int E) {
    int e = blockIdx.x * 256 + threadIdx.x;
    if (e < E) atomicAdd(&cnt[ei[E + e]], 1);
}

__global__ __launch_bounds__(256) void k_scan1(const int* __restrict__ cnt, int* __restrict__ row_ptr,
                                               int* __restrict__ blockSums, int n) {
    __shared__ int sdata[256];
    int tid = threadIdx.x;
    int base = blockIdx.x * 1024 + tid * 4;
    int v0 = (base + 0 < n) ? cnt[base + 0] : 0;
    int v1 = (base + 1 < n) ? cnt[base + 1] : 0;
    int v2 = (base + 2 < n) ? cnt[base + 2] : 0;
    int v3 = (base + 3 < n) ? cnt[base + 3] : 0;
    int t = v0 + v1 + v2 + v3;
    int x = t;
    sdata[tid] = x; __syncthreads();
    for (int off = 1; off < 256; off <<= 1) {
        int y = (tid >= off) ? sdata[tid - off] : 0;
        __syncthreads();
        x += y;
        sdata[tid] = x;
        __syncthreads();
    }
    int p = x - t;  // exclusive prefix within block
    if (base + 0 < n) row_ptr[base + 0] = p;
    if (base + 1 < n) row_ptr[base + 1] = p + v0;
    if (base + 2 < n) row_ptr[base + 2] = p + v0 + v1;
    if (base + 3 < n) row_ptr[base + 3] = p + v0 + v1 + v2;
    if (tid == 255) blockSums[blockIdx.x] = x;
}

__global__ __launch_bounds__(128) void k_scan2(const int* __restrict__ blockSums, int* __restrict__ blockOffs, int nb) {
    __shared__ int sdata[128];
    int tid = threadIdx.x;
    int t = (tid < nb) ? blockSums[tid] : 0;
    int x = t;
    sdata[tid] = x; __syncthreads();
    for (int off = 1; off < 128; off <<= 1) {
        int y = (tid >= off) ? sdata[tid - off] : 0;
        __syncthreads();
        x += y;
        sdata[tid] = x;
        __syncthreads();
    }
    blockOffs[tid] = x - t;  // exclusive
}

__global__ __launch_bounds__(256) void k_scan3(int* __restrict__ row_ptr, const int* __restrict__ blockOffs, int n) {
    int add = blockOffs[blockIdx.x];
    int base = blockIdx.x * 1024 + threadIdx.x * 4;
    if (base + 0 < n) row_ptr[base + 0] += add;
    if (base + 1 < n) row_ptr[base + 1] += add;
    if (base + 2 < n) row_ptr[base + 2] += add;
    if (base + 3 < n) row_ptr[base + 3] += add;
}

// bucket_head[b] = CSR offset of first node in bucket b (512 nodes per bucket)
__global__ __launch_bounds__(256) void k_bhead(const int* __restrict__ row_ptr, int* __restrict__ bucket_head,
                                               int n, int E, int nbuck) {
    int b = threadIdx.x;
    if (b >= nbuck) return;
    int v = b << 9;
    bucket_head[b] = (v < n) ? row_ptr[v] : E;
}

// Pass A: bin edges by dst bucket.
__global__ __launch_bounds__(256) void k_binA(const int* __restrict__ ei, int* __restrict__ bucket_head,
                                              int2* __restrict__ tmp8, int* __restrict__ tmpd, int E) {
    __shared__ int hist[256], base[256], fill[256];
    int tid = threadIdx.x;
    hist[tid] = 0; fill[tid] = 0;
    __syncthreads();
    int e0 = blockIdx.x * 4096;
    int d[16];
#pragma unroll
    for (int k = 0; k < 16; ++k) {
        int e = e0 + k * 256 + tid;
        d[k] = -1;
        if (e < E) { d[k] = ei[E + e]; atomicAdd(&hist[d[k] >> 9], 1); }
    }
    __syncthreads();
    if (hist[tid]) base[tid] = atomicAdd(&bucket_head[tid], hist[tid]);
    __syncthreads();
#pragma unroll
    for (int k = 0; k < 16; ++k) {
        if (d[k] >= 0) {
            int e = e0 + k * 256 + tid;
            int b = d[k] >> 9;
            int p = base[b] + atomicAdd(&fill[b], 1);
            tmp8[p] = make_int2(ei[e], e);
            tmpd[p] = d[k];
        }
    }
}

// Pass B: one block per bucket; scatter confined to a small window.
__global__ __launch_bounds__(256) void k_binB(const int2* __restrict__ tmp8, const int* __restrict__ tmpd,
                                              const int* __restrict__ row_ptr, int* __restrict__ csr_src,
                                              int* __restrict__ csr_eid, int n, int E) {
    __shared__ int lhead[512];
    int b = blockIdx.x;
    int lo = b << 9;
    int hi = lo + 512; if (hi > n) hi = n;
    int tid = threadIdx.x;
    for (int i = tid; i < hi - lo; i += 256) lhead[i] = row_ptr[lo + i];
    __syncthreads();
    int jlo = row_ptr[lo];
    int jhi = (hi < n) ? row_ptr[hi] : E;
    for (int j = jlo + tid; j < jhi; j += 256) {
        int dd = tmpd[j];
        int2 se = tmp8[j];
        int pos = atomicAdd(&lhead[dd - lo], 1);
        csr_src[pos] = se.x;
        csr_eid[pos] = se.y;
    }
}

// agg_e[v] = sum of edge_attr over incoming edges. No atomics.
__global__ __launch_bounds__(256) void k_agge(const int* __restrict__ csr_eid, const float* __restrict__ ea,
                                              const int* __restrict__ row_ptr, const int* __restrict__ cnt,
                                              float* __restrict__ agg_e, int n) {
    int v = blockIdx.x * 256 + threadIdx.x;
    if (v >= n) return;
    int start = row_ptr[v];
    int deg = cnt[v];
    float4 a = make_float4(0.f, 0.f, 0.f, 0.f);
    for (int i = 0; i < deg; ++i) {
        int eid = csr_eid[start + i];
        float4 t = ((const float4*)ea)[eid];
        a.x += t.x; a.y += t.y; a.z += t.z; a.w += t.w;
    }
    ((float4*)agg_e)[v] = a;
}

// ---------------- one-time conversions ----------------
// x fp32 [n][128] -> sliced bf16 xs[s][n][16], s = blockIdx.y
__global__ __launch_bounds__(256) void k_cvt_s(const float* __restrict__ x, ushort* __restrict__ xs, int n) {
    int v = blockIdx.x * 256 + threadIdx.x;
    int s = blockIdx.y;
    if (v >= n) return;
    size_t sl = (size_t)n * 16;
    const float4* src = (const float4*)(x + (size_t)v * 128 + s * 16);
    float4 a = src[0], b = src[1], c = src[2], d = src[3];
    uint4 o0, o1;
    o0.x = f2bf(a.x) | (f2bf(a.y) << 16); o0.y = f2bf(a.z) | (f2bf(a.w) << 16);
    o0.z = f2bf(b.x) | (f2bf(b.y) << 16); o0.w = f2bf(b.z) | (f2bf(b.w) << 16);
    o1.x = f2bf(c.x) | (f2bf(c.y) << 16); o1.y = f2bf(c.z) | (f2bf(c.w) << 16);
    o1.z = f2bf(d.x) | (f2bf(d.y) << 16); o1.w = f2bf(d.z) | (f2bf(d.w) << 16);
    uint4* dst = (uint4*)(xs + (size_t)s * sl + (size_t)v * 16);
    dst[0] = o0; dst[1] = o1;
}

// Wt[n][k] = bf16(W[k][n]) for the 128x128 node-feature part of W
__global__ __launch_bounds__(256) void k_cvtW(const float* __restrict__ W, ushort* __restrict__ Wt) {
    int i = blockIdx.x * 256 + threadIdx.x;
    if (i >= 16384) return;
    int nn = i & 127, kk = i >> 7;
    Wt[nn * 128 + kk] = (ushort)f2bf(W[kk * 128 + nn]);
}

// ---------------- per-layer: sliced gather aggregation ----------------
// slice = blockIdx%8 -> pinned to one XCD (round-robin dispatch); slice data
// (3.2MB) stays L2-resident. Wave = 32 lane-pairs, each pair owns one node.
__global__ __launch_bounds__(256) void k_gather_s(const ushort* __restrict__ xs, ushort* __restrict__ aggs,
                                                  const int* __restrict__ row_ptr, const int* __restrict__ cnt,
                                                  const int* __restrict__ csr_src, int n) {
    int s = blockIdx.x & 7;
    int grp = blockIdx.x >> 3;
    int lane = threadIdx.x & 63;
    int wave = threadIdx.x >> 6;
    int p = lane >> 1, h = lane & 1;
    int v = grp * 128 + wave * 32 + p;
    size_t sl = (size_t)n * 16;
    const uint4v* x4 = (const uint4v*)(xs + (size_t)s * sl);
    uint4v* a4 = (uint4v*)(aggs + (size_t)s * sl);
    float acc[8] = {0.f, 0.f, 0.f, 0.f, 0.f, 0.f, 0.f, 0.f};
    int start = 0, deg = 0;
    if (v < n) {
        start = row_ptr[v]; deg = cnt[v];
        uint4v w = x4[(size_t)v * 2 + h];   // self loop
        acc[0] = bf2f((ushort)(w.x & 0xffffu)); acc[1] = bf2f((ushort)(w.x >> 16));
        acc[2] = bf2f((ushort)(w.y & 0xffffu)); acc[3] = bf2f((ushort)(w.y >> 16));
        acc[4] = bf2f((ushort)(w.z & 0xffffu)); acc[5] = bf2f((ushort)(w.z >> 16));
        acc[6] = bf2f((ushort)(w.w & 0xffffu)); acc[7] = bf2f((ushort)(w.w >> 16));
    }
    for (int i = 0; i < deg; ++i) {
        int src = __builtin_nontemporal_load(csr_src + start + i);
        uint4v w = x4[(size_t)src * 2 + h];
        acc[0] += bf2f((ushort)(w.x & 0xffffu)); acc[1] += bf2f((ushort)(w.x >> 16));
        acc[2] += bf2f((ushort)(w.y & 0xffffu)); acc[3] += bf2f((ushort)(w.y >> 16));
        acc[4] += bf2f((ushort)(w.z & 0xffffu)); acc[5] += bf2f((ushort)(w.z >> 16));
        acc[6] += bf2f((ushort)(w.w & 0xffffu)); acc[7] += bf2f((ushort)(w.w >> 16));
    }
    if (v < n) {
        uint4v o;
        o.x = f2bf(acc[0]) | (f2bf(acc[1]) << 16);
        o.y = f2bf(acc[2]) | (f2bf(acc[3]) << 16);
        o.z = f2bf(acc[4]) | (f2bf(acc[5]) << 16);
        o.w = f2bf(acc[6]) | (f2bf(acc[7]) << 16);
        __builtin_nontemporal_store(o, &a4[(size_t)v * 2 + h]);
    }
}

// ---------------- per-layer: MFMA GEMM + edge-bias + bias + relu ----------------
// A from sliced aggs; out written sliced to xs_out.
__global__ __launch_bounds__(256) void k_gemm_mfma(const ushort* __restrict__ aggs, ushort* __restrict__ xs_out,
                                                   const float* __restrict__ agg_e, const ushort* __restrict__ Wt,
                                                   const float* __restrict__ W, const float* __restrict__ bias, int n) {
    __shared__ float we[512];
    __shared__ float bl[128];
    int tid = threadIdx.x;
    for (int i = tid; i < 512; i += 256) we[i] = W[128 * 128 + i];
    if (tid < 128) bl[tid] = bias[tid];
    __syncthreads();

    int wave = tid >> 6, lane = tid & 63;
    int r16 = lane & 15;
    int kc = (lane >> 4) * 8;
    int row0 = blockIdx.x * 64 + wave * 16;
    size_t sl = (size_t)n * 16;

    int arr = row0 + r16;
    size_t arow = (size_t)(arr < n ? arr : (n - 1)) * 16;

    f32x4 acc[8];
#pragma unroll
    for (int t = 0; t < 8; ++t) acc[t] = (f32x4){0.f, 0.f, 0.f, 0.f};

#pragma unroll
    for (int ks = 0; ks < 4; ++ks) {
        int f0 = ks * 32 + kc;
        short8 a = *(const short8*)(aggs + (size_t)(f0 >> 4) * sl + arow + (f0 & 15));
#pragma unroll
        for (int nt = 0; nt < 8; ++nt) {
            short8 b = *(const short8*)(Wt + (size_t)(nt * 16 + r16) * 128 + ks * 32 + kc);
            acc[nt] = __builtin_amdgcn_mfma_f32_16x16x32_bf16(a, b, acc[nt], 0, 0, 0);
        }
    }

#pragma unroll
    for (int r = 0; r < 4; ++r) {
        int row = row0 + (lane >> 4) * 4 + r;
        if (row >= n) continue;
        float4 e = *(const float4*)(agg_e + (size_t)row * 4);
#pragma unroll
        for (int nt = 0; nt < 8; ++nt) {
            int col = nt * 16 + r16;
            float o = acc[nt][r] + bl[col] + e.x * we[col] + e.y * we[128 + col]
                    + e.z * we[256 + col] + e.w * we[384 + col];
            o = fmaxf(o, 0.f);
            xs_out[(size_t)nt * sl + (size_t)row * 16 + r16] = (ushort)f2bf(o);
        }
    }
}

// ---------------- pooling (segmented: batch is sorted) ----------------

__global__ __launch_bounds__(256) void k_bounds(const int* __restrict__ batch, int* __restrict__ gstart,
                                                int n, int G) {
    int i = blockIdx.x * 256 + threadIdx.x;
    if (i >= n) return;
    int g = batch[i];
    if (i == 0) {
        for (int q = 0; q <= g; ++q) gstart[q] = 0;
    } else {
        int gp = batch[i - 1];
        for (int q = gp + 1; q <= g; ++q) gstart[q] = i;
    }
    if (i == n - 1) {
        for (int q = g + 1; q <= G; ++q) gstart[q] = n;
    }
}

#define POOL_S 16
__global__ __launch_bounds__(128) void k_pool2(const ushort* __restrict__ xs, const int* __restrict__ gstart,
                                               float* __restrict__ pooled, int n) {
    int g = blockIdx.x / POOL_S;
    int s = blockIdx.x % POOL_S;
    int t = threadIdx.x;
    size_t sl = (size_t)n * 16;
    const ushort* base = xs + (size_t)(t >> 4) * sl + (t & 15);
    int lo = gstart[g], hi = gstart[g + 1];
    int len = hi - lo;
    if (len <= 0) return;
    int chunk = (len + POOL_S - 1) / POOL_S;
    int a = lo + s * chunk;
    int b = a + chunk; if (b > hi) b = hi;
    if (a >= b) return;
    float acc = 0.f;
    for (int v = a; v < b; ++v) acc += bf2f(base[(size_t)v * 16]);
    atomicAdd(&pooled[g * 128 + t], acc);
}

__global__ __launch_bounds__(128) void k_final(const float* __restrict__ pooled, const int* __restrict__ gstart,
                                               const float* __restrict__ Wout, const float* __restrict__ bout,
                                               float* __restrict__ out, int G) {
    int g = threadIdx.x;
    if (g >= G) return;
    float c = (float)(gstart[g + 1] - gstart[g]);
    if (c < 1.f) c = 1.f;
    float l0 = bout[0], l1 = bout[1], l2 = bout[2], l3 = bout[3];
    for (int k = 0; k < 128; ++k) {
        float p = pooled[g * 128 + k] / c;
        l0 += p * Wout[k * 4 + 0];
        l1 += p * Wout[k * 4 + 1];
        l2 += p * Wout[k * 4 + 2];
        l3 += p * Wout[k * 4 + 3];
    }
    float m = fmaxf(fmaxf(l0, l1), fmaxf(l2, l3));
    float s = expf(l0 - m) + expf(l1 - m) + expf(l2 - m) + expf(l3 - m);
    float ls = logf(s);
    out[g * 4 + 0] = l0 - m - ls;
    out[g * 4 + 1] = l1 - m - ls;
    out[g * 4 + 2] = l2 - m - ls;
    out[g * 4 + 3] = l3 - m - ls;
}

extern "C" void kernel_launch(void* const* d_in, const int* in_sizes, int n_in,
                              void* d_out, int out_size, void* d_ws, size_t ws_size,
                              hipStream_t stream) {
    const float* x    = (const float*)d_in[0];
    const int*   ei   = (const int*)d_in[1];
    const float* ea   = (const float*)d_in[2];
    const int*   bat  = (const int*)d_in[3];
    const float* W0   = (const float*)d_in[4];
    const float* b0   = (const float*)d_in[5];
    const float* W1   = (const float*)d_in[6];
    const float* b1   = (const float*)d_in[7];
    const float* W2   = (const float*)d_in[8];
    const float* b2   = (const float*)d_in[9];
    const float* Wout = (const float*)d_in[10];
    const float* bout = (const float*)d_in[11];
    float* out = (float*)d_out;

    int n = in_sizes[0] / 128;
    int E = in_sizes[1] / 2;
    int G = out_size / 4;
    int nbuck = (n + 511) >> 9;   // 196 for n=100000 (max 256 supported)

    char* w = (char*)d_ws;
    auto alloc = [&](size_t bytes) { char* p = w; w += (bytes + 255) & ~(size_t)255; return p; };
    int* cnt         = (int*)alloc((size_t)n * 4);
    int* row_ptr     = (int*)alloc((size_t)n * 4);
    int* blockSums   = (int*)alloc(4096);
    int* blockOffs   = (int*)alloc(4096);
    int* bucket_head = (int*)alloc(1024);
    int* csr_src     = (int*)alloc((size_t)E * 4);
    int* csr_eid     = (int*)alloc((size_t)E * 4);
    int2* tmp8       = (int2*)alloc((size_t)E * 8);
    int* tmpd        = (int*)alloc((size_t)E * 4);
    float* agg_e     = (float*)alloc((size_t)n * 16);
    float* pooled    = (float*)alloc((size_t)G * 128 * 4);
    int* gstart      = (int*)alloc((size_t)(G + 4) * 4);
    ushort* xs       = (ushort*)alloc((size_t)n * 128 * 2);
    ushort* aggs     = (ushort*)alloc((size_t)n * 128 * 2);
    ushort* Wt0      = (ushort*)alloc(128 * 128 * 2);
    ushort* Wt1      = (ushort*)alloc(128 * 128 * 2);
    ushort* Wt2      = (ushort*)alloc(128 * 128 * 2);

    hipMemsetAsync(cnt, 0, (size_t)n * 4, stream);
    hipMemsetAsync(pooled, 0, (size_t)G * 128 * 4, stream);

    int eb = (E + 255) / 256;
    int nb = (n + 1023) / 1024;   // 98 for n=100000, fits k_scan2's 128 slots
    k_count<<<eb, 256, 0, stream>>>(ei, cnt, E);
    k_scan1<<<nb, 256, 0, stream>>>(cnt, row_ptr, blockSums, n);
    k_scan2<<<1, 128, 0, stream>>>(blockSums, blockOffs, nb);
    k_scan3<<<nb, 256, 0, stream>>>(row_ptr, blockOffs, n);
    k_bhead<<<1, 256, 0, stream>>>(row_ptr, bucket_head, n, E, nbuck);
    k_binA<<<(E + 4095) / 4096, 256, 0, stream>>>(ei, bucket_head, tmp8, tmpd, E);
    k_binB<<<nbuck, 256, 0, stream>>>(tmp8, tmpd, row_ptr, csr_src, csr_eid, n, E);
    k_agge<<<(n + 255) / 256, 256, 0, stream>>>(csr_eid, ea, row_ptr, cnt, agg_e, n);
    k_bounds<<<(n + 255) / 256, 256, 0, stream>>>(bat, gstart, n, G);
    {
        dim3 cg((n + 255) / 256, 8);
        k_cvt_s<<<cg, 256, 0, stream>>>(x, xs, n);
    }
    k_cvtW<<<64, 256, 0, stream>>>(W0, Wt0);
    k_cvtW<<<64, 256, 0, stream>>>(W1, Wt1);
    k_cvtW<<<64, 256, 0, stream>>>(W2, Wt2);

    int gb = 8 * ((n + 127) / 128);   // slice-pinned gather blocks
    int mb = (n + 63) / 64;           // 64 rows per GEMM block

    k_gather_s<<<gb, 256, 0, stream>>>(xs, aggs, row_ptr, cnt, csr_src, n);
    k_gemm_mfma<<<mb, 256, 0, stream>>>(aggs, xs, agg_e, Wt0, W0, b0, n);
    k_gather_s<<<gb, 256, 0, stream>>>(xs, aggs, row_ptr, cnt, csr_src, n);
    k_gemm_mfma<<<mb, 256, 0, stream>>>(aggs, xs, agg_e, Wt1, W1, b1, n);
    k_gather_s<<<gb, 256, 0, stream>>>(xs, aggs, row_ptr, cnt, csr_src, n);
    k_gemm_mfma<<<mb, 256, 0, stream>>>(aggs, xs, agg_e, Wt2, W2, b2, n);

    k_pool2<<<G * POOL_S, 128, 0, stream>>>(xs, gstart, pooled, n);
    k_final<<<1, 128, 0, stream>>>(pooled, gstart, Wout, bout, out, G);
}

// Round 9
// 564.332 us; speedup vs baseline: 1.6629x; 1.6629x over previous
//
#include <hip/hip_runtime.h>

typedef __attribute__((ext_vector_type(8))) short short8;
typedef __attribute__((ext_vector_type(4))) float f32x4;
typedef __attribute__((ext_vector_type(4))) unsigned uint4v;

// ---------------- bf16 helpers ----------------
__device__ inline unsigned f2bf(float f) {
    unsigned u = __float_as_uint(f);
    u += 0x7fffu + ((u >> 16) & 1u);   // round-to-nearest-even
    return u >> 16;
}
__device__ inline float bf2f(ushort h) { return __uint_as_float(((unsigned)h) << 16); }

// ---------------- CSR build ----------------

__global__ __launch_bounds__(256) void k_count(const int* __restrict__ ei, int* __restrict__ cnt, int E) {
    int e = blockIdx.x * 256 + threadIdx.x;
    if (e < E) atomicAdd(&cnt[ei[E + e]], 1);
}

__global__ __launch_bounds__(256) void k_scan1(const int* __restrict__ cnt, int* __restrict__ row_ptr,
                                               int* __restrict__ blockSums, int n) {
    __shared__ int sdata[256];
    int tid = threadIdx.x;
    int base = blockIdx.x * 1024 + tid * 4;
    int v0 = (base + 0 < n) ? cnt[base + 0] : 0;
    int v1 = (base + 1 < n) ? cnt[base + 1] : 0;
    int v2 = (base + 2 < n) ? cnt[base + 2] : 0;
    int v3 = (base + 3 < n) ? cnt[base + 3] : 0;
    int t = v0 + v1 + v2 + v3;
    int x = t;
    sdata[tid] = x; __syncthreads();
    for (int off = 1; off < 256; off <<= 1) {
        int y = (tid >= off) ? sdata[tid - off] : 0;
        __syncthreads();
        x += y;
        sdata[tid] = x;
        __syncthreads();
    }
    int p = x - t;  // exclusive prefix within block
    if (base + 0 < n) row_ptr[base + 0] = p;
    if (base + 1 < n) row_ptr[base + 1] = p + v0;
    if (base + 2 < n) row_ptr[base + 2] = p + v0 + v1;
    if (base + 3 < n) row_ptr[base + 3] = p + v0 + v1 + v2;
    if (tid == 255) blockSums[blockIdx.x] = x;
}

__global__ __launch_bounds__(128) void k_scan2(const int* __restrict__ blockSums, int* __restrict__ blockOffs, int nb) {
    __shared__ int sdata[128];
    int tid = threadIdx.x;
    int t = (tid < nb) ? blockSums[tid] : 0;
    int x = t;
    sdata[tid] = x; __syncthreads();
    for (int off = 1; off < 128; off <<= 1) {
        int y = (tid >= off) ? sdata[tid - off] : 0;
        __syncthreads();
        x += y;
        sdata[tid] = x;
        __syncthreads();
    }
    blockOffs[tid] = x - t;  // exclusive
}

__global__ __launch_bounds__(256) void k_scan3(int* __restrict__ row_ptr, const int* __restrict__ blockOffs, int n) {
    int add = blockOffs[blockIdx.x];
    int base = blockIdx.x * 1024 + threadIdx.x * 4;
    if (base + 0 < n) row_ptr[base + 0] += add;
    if (base + 1 < n) row_ptr[base + 1] += add;
    if (base + 2 < n) row_ptr[base + 2] += add;
    if (base + 3 < n) row_ptr[base + 3] += add;
}

// bucket_head[b] = CSR offset of first node in bucket b (512 nodes per bucket)
__global__ __launch_bounds__(256) void k_bhead(const int* __restrict__ row_ptr, int* __restrict__ bucket_head,
                                               int n, int E, int nbuck) {
    int b = threadIdx.x;
    if (b >= nbuck) return;
    int v = b << 9;
    bucket_head[b] = (v < n) ? row_ptr[v] : E;
}

// Pass A: bin edges by dst bucket. tmpA = src | (dst&511)<<17  (n < 2^17),
// tmpE = edge_attr as bf16x4. ea read is contiguous (e-ordered).
__global__ __launch_bounds__(256) void k_binA(const int* __restrict__ ei, const float* __restrict__ ea,
                                              int* __restrict__ bucket_head,
                                              int* __restrict__ tmpA, uint2* __restrict__ tmpE, int E) {
    __shared__ int hist[256], base[256], fill[256];
    int tid = threadIdx.x;
    hist[tid] = 0; fill[tid] = 0;
    __syncthreads();
    int e0 = blockIdx.x * 4096;
    int d[16];
#pragma unroll
    for (int k = 0; k < 16; ++k) {
        int e = e0 + k * 256 + tid;
        d[k] = -1;
        if (e < E) { d[k] = ei[E + e]; atomicAdd(&hist[d[k] >> 9], 1); }
    }
    __syncthreads();
    if (hist[tid]) base[tid] = atomicAdd(&bucket_head[tid], hist[tid]);
    __syncthreads();
#pragma unroll
    for (int k = 0; k < 16; ++k) {
        if (d[k] >= 0) {
            int e = e0 + k * 256 + tid;
            int b = d[k] >> 9;
            int p = base[b] + atomicAdd(&fill[b], 1);
            float4 a = ((const float4*)ea)[e];
            tmpA[p] = ei[e] | ((d[k] & 511) << 17);
            tmpE[p] = make_uint2(f2bf(a.x) | (f2bf(a.y) << 16), f2bf(a.z) | (f2bf(a.w) << 16));
        }
    }
}

// Pass B: one block per bucket; scatter confined to a small window.
__global__ __launch_bounds__(256) void k_binB(const int* __restrict__ tmpA, const uint2* __restrict__ tmpE,
                                              const int* __restrict__ row_ptr, int* __restrict__ csr_src,
                                              uint2* __restrict__ csr_ea, int n, int E) {
    __shared__ int lhead[512];
    int b = blockIdx.x;
    int lo = b << 9;
    int hi = lo + 512; if (hi > n) hi = n;
    int tid = threadIdx.x;
    for (int i = tid; i < hi - lo; i += 256) lhead[i] = row_ptr[lo + i];
    __syncthreads();
    int jlo = row_ptr[lo];
    int jhi = (hi < n) ? row_ptr[hi] : E;
    for (int j = jlo + tid; j < jhi; j += 256) {
        int w = tmpA[j];
        uint2 eav = tmpE[j];
        int pos = atomicAdd(&lhead[w >> 17], 1);
        csr_src[pos] = w & 0x1FFFF;
        csr_ea[pos] = eav;
    }
}

// agg_e[v] = sum of bf16 edge_attr over incoming edges; contiguous csr_ea reads.
__global__ __launch_bounds__(256) void k_agge(const uint2* __restrict__ csr_ea,
                                              const int* __restrict__ row_ptr, const int* __restrict__ cnt,
                                              float* __restrict__ agg_e, int n) {
    int v = blockIdx.x * 256 + threadIdx.x;
    if (v >= n) return;
    int start = row_ptr[v];
    int deg = cnt[v];
    float4 a = make_float4(0.f, 0.f, 0.f, 0.f);
    for (int i = 0; i < deg; ++i) {
        uint2 t = csr_ea[start + i];
        a.x += bf2f((ushort)(t.x & 0xffffu)); a.y += bf2f((ushort)(t.x >> 16));
        a.z += bf2f((ushort)(t.y & 0xffffu)); a.w += bf2f((ushort)(t.y >> 16));
    }
    ((float4*)agg_e)[v] = a;
}

// ---------------- one-time conversions ----------------
__global__ __launch_bounds__(256) void k_cvt(const float* __restrict__ in, ushort* __restrict__ out, int total4) {
    int i = blockIdx.x * 256 + threadIdx.x;
    if (i >= total4) return;
    float4 v = ((const float4*)in)[i];
    unsigned lo = f2bf(v.x) | (f2bf(v.y) << 16);
    unsigned hi = f2bf(v.z) | (f2bf(v.w) << 16);
    ((uint2*)out)[i] = make_uint2(lo, hi);
}

// Wt[n][k] = bf16(W[k][n]) for the 128x128 node-feature part of W
__global__ __launch_bounds__(256) void k_cvtW(const float* __restrict__ W, ushort* __restrict__ Wt) {
    int i = blockIdx.x * 256 + threadIdx.x;
    if (i >= 16384) return;
    int nn = i & 127, kk = i >> 7;
    Wt[nn * 128 + kk] = (ushort)f2bf(W[kk * 128 + nn]);
}

// ---------------- per-layer: gather aggregation ----------------
// Wave per node; 4 groups of 16 lanes; each group handles every 4th edge,
// lane loads 16B -> 4 rows in flight. Nontemporal output store keeps L2 for xb.
__global__ __launch_bounds__(256) void k_gather_b(const ushort* __restrict__ xb, ushort* __restrict__ aggb,
                                                  const int* __restrict__ row_ptr, const int* __restrict__ cnt,
                                                  const int* __restrict__ csr_src, int n) {
    int wid = (blockIdx.x * 256 + threadIdx.x) >> 6;
    int lane = threadIdx.x & 63;
    if (wid >= n) return;
    int g = lane >> 4, t = lane & 15;
    const uint4v* x4 = (const uint4v*)xb;   // row = 16 uint4
    float acc[8];
    {
        uint4v v = {0u, 0u, 0u, 0u};
        if (g == 0) v = x4[(size_t)wid * 16 + t];  // self loop
        acc[0] = bf2f((ushort)(v.x & 0xffffu)); acc[1] = bf2f((ushort)(v.x >> 16));
        acc[2] = bf2f((ushort)(v.y & 0xffffu)); acc[3] = bf2f((ushort)(v.y >> 16));
        acc[4] = bf2f((ushort)(v.z & 0xffffu)); acc[5] = bf2f((ushort)(v.z >> 16));
        acc[6] = bf2f((ushort)(v.w & 0xffffu)); acc[7] = bf2f((ushort)(v.w >> 16));
    }
    int start = row_ptr[wid];
    int deg = cnt[wid];
    for (int i = g; i < deg; i += 4) {
        int s = __builtin_nontemporal_load(csr_src + start + i);   // broadcast across 16 lanes
        uint4v v = x4[(size_t)s * 16 + t];
        acc[0] += bf2f((ushort)(v.x & 0xffffu)); acc[1] += bf2f((ushort)(v.x >> 16));
        acc[2] += bf2f((ushort)(v.y & 0xffffu)); acc[3] += bf2f((ushort)(v.y >> 16));
        acc[4] += bf2f((ushort)(v.z & 0xffffu)); acc[5] += bf2f((ushort)(v.z >> 16));
        acc[6] += bf2f((ushort)(v.w & 0xffffu)); acc[7] += bf2f((ushort)(v.w >> 16));
    }
#pragma unroll
    for (int j = 0; j < 8; ++j) {
        acc[j] += __shfl_xor(acc[j], 16);
        acc[j] += __shfl_xor(acc[j], 32);
    }
    if (lane < 16) {
        uint4v o;
        o.x = f2bf(acc[0]) | (f2bf(acc[1]) << 16);
        o.y = f2bf(acc[2]) | (f2bf(acc[3]) << 16);
        o.z = f2bf(acc[4]) | (f2bf(acc[5]) << 16);
        o.w = f2bf(acc[6]) | (f2bf(acc[7]) << 16);
        __builtin_nontemporal_store(o, (uint4v*)(aggb + (size_t)wid * 128 + lane * 8));
    }
}

// ---------------- per-layer: MFMA GEMM + edge-bias + bias + relu ----------------
__global__ __launch_bounds__(256) void k_gemm_mfma(const ushort* __restrict__ aggb, ushort* __restrict__ xb_out,
                                                   const float* __restrict__ agg_e, const ushort* __restrict__ Wt,
                                                   const float* __restrict__ W, const float* __restrict__ bias, int n) {
    __shared__ float we[512];
    __shared__ float bl[128];
    int tid = threadIdx.x;
    for (int i = tid; i < 512; i += 256) we[i] = W[128 * 128 + i];
    if (tid < 128) bl[tid] = bias[tid];
    __syncthreads();

    int wave = tid >> 6, lane = tid & 63;
    int r16 = lane & 15;
    int kc = (lane >> 4) * 8;
    int row0 = blockIdx.x * 64 + wave * 16;

    int arr = row0 + r16;
    const ushort* arow = aggb + (size_t)(arr < n ? arr : (n - 1)) * 128 + kc;

    f32x4 acc[8];
#pragma unroll
    for (int t = 0; t < 8; ++t) acc[t] = (f32x4){0.f, 0.f, 0.f, 0.f};

#pragma unroll
    for (int ks = 0; ks < 4; ++ks) {
        short8 a = *(const short8*)(arow + ks * 32);
#pragma unroll
        for (int nt = 0; nt < 8; ++nt) {
            short8 b = *(const short8*)(Wt + (size_t)(nt * 16 + r16) * 128 + ks * 32 + kc);
            acc[nt] = __builtin_amdgcn_mfma_f32_16x16x32_bf16(a, b, acc[nt], 0, 0, 0);
        }
    }

#pragma unroll
    for (int r = 0; r < 4; ++r) {
        int row = row0 + (lane >> 4) * 4 + r;
        if (row >= n) continue;
        float4 e = *(const float4*)(agg_e + (size_t)row * 4);
#pragma unroll
        for (int nt = 0; nt < 8; ++nt) {
            int col = nt * 16 + r16;
            float o = acc[nt][r] + bl[col] + e.x * we[col] + e.y * we[128 + col]
                    + e.z * we[256 + col] + e.w * we[384 + col];
            o = fmaxf(o, 0.f);
            xb_out[(size_t)row * 128 + col] = (ushort)f2bf(o);
        }
    }
}

// ---------------- pooling (segmented: batch is sorted) ----------------

__global__ __launch_bounds__(256) void k_bounds(const int* __restrict__ batch, int* __restrict__ gstart,
                                                int n, int G) {
    int i = blockIdx.x * 256 + threadIdx.x;
    if (i >= n) return;
    int g = batch[i];
    if (i == 0) {
        for (int q = 0; q <= g; ++q) gstart[q] = 0;
    } else {
        int gp = batch[i - 1];
        for (int q = gp + 1; q <= g; ++q) gstart[q] = i;
    }
    if (i == n - 1) {
        for (int q = g + 1; q <= G; ++q) gstart[q] = n;
    }
}

#define POOL_S 16
__global__ __launch_bounds__(128) void k_pool2(const ushort* __restrict__ xb, const int* __restrict__ gstart,
                                               float* __restrict__ pooled) {
    int g = blockIdx.x / POOL_S;
    int s = blockIdx.x % POOL_S;
    int t = threadIdx.x;
    int lo = gstart[g], hi = gstart[g + 1];
    int len = hi - lo;
    if (len <= 0) return;
    int chunk = (len + POOL_S - 1) / POOL_S;
    int a = lo + s * chunk;
    int b = a + chunk; if (b > hi) b = hi;
    if (a >= b) return;
    float acc = 0.f;
    for (int v = a; v < b; ++v) acc += bf2f(xb[(size_t)v * 128 + t]);
    atomicAdd(&pooled[g * 128 + t], acc);
}

__global__ __launch_bounds__(128) void k_final(const float* __restrict__ pooled, const int* __restrict__ gstart,
                                               const float* __restrict__ Wout, const float* __restrict__ bout,
                                               float* __restrict__ out, int G) {
    int g = threadIdx.x;
    if (g >= G) return;
    float c = (float)(gstart[g + 1] - gstart[g]);
    if (c < 1.f) c = 1.f;
    float l0 = bout[0], l1 = bout[1], l2 = bout[2], l3 = bout[3];
    for (int k = 0; k < 128; ++k) {
        float p = pooled[g * 128 + k] / c;
        l0 += p * Wout[k * 4 + 0];
        l1 += p * Wout[k * 4 + 1];
        l2 += p * Wout[k * 4 + 2];
        l3 += p * Wout[k * 4 + 3];
    }
    float m = fmaxf(fmaxf(l0, l1), fmaxf(l2, l3));
    float s = expf(l0 - m) + expf(l1 - m) + expf(l2 - m) + expf(l3 - m);
    float ls = logf(s);
    out[g * 4 + 0] = l0 - m - ls;
    out[g * 4 + 1] = l1 - m - ls;
    out[g * 4 + 2] = l2 - m - ls;
    out[g * 4 + 3] = l3 - m - ls;
}

extern "C" void kernel_launch(void* const* d_in, const int* in_sizes, int n_in,
                              void* d_out, int out_size, void* d_ws, size_t ws_size,
                              hipStream_t stream) {
    const float* x    = (const float*)d_in[0];
    const int*   ei   = (const int*)d_in[1];
    const float* ea   = (const float*)d_in[2];
    const int*   bat  = (const int*)d_in[3];
    const float* W0   = (const float*)d_in[4];
    const float* b0   = (const float*)d_in[5];
    const float* W1   = (const float*)d_in[6];
    const float* b1   = (const float*)d_in[7];
    const float* W2   = (const float*)d_in[8];
    const float* b2   = (const float*)d_in[9];
    const float* Wout = (const float*)d_in[10];
    const float* bout = (const float*)d_in[11];
    float* out = (float*)d_out;

    int n = in_sizes[0] / 128;   // n < 2^17 assumed by tmpA packing (n = 100000 here)
    int E = in_sizes[1] / 2;
    int G = out_size / 4;
    int nbuck = (n + 511) >> 9;   // 196 for n=100000 (max 256 supported)

    char* w = (char*)d_ws;
    auto alloc = [&](size_t bytes) { char* p = w; w += (bytes + 255) & ~(size_t)255; return p; };
    int* cnt         = (int*)alloc((size_t)n * 4);
    int* row_ptr     = (int*)alloc((size_t)n * 4);
    int* blockSums   = (int*)alloc(4096);
    int* blockOffs   = (int*)alloc(4096);
    int* bucket_head = (int*)alloc(1024);
    int* csr_src     = (int*)alloc((size_t)E * 4);
    uint2* csr_ea    = (uint2*)alloc((size_t)E * 8);
    int* tmpA        = (int*)alloc((size_t)E * 4);
    uint2* tmpE      = (uint2*)alloc((size_t)E * 8);
    float* agg_e     = (float*)alloc((size_t)n * 16);
    float* pooled    = (float*)alloc((size_t)G * 128 * 4);
    int* gstart      = (int*)alloc((size_t)(G + 4) * 4);
    ushort* xb       = (ushort*)alloc((size_t)n * 128 * 2);
    ushort* aggb     = (ushort*)alloc((size_t)n * 128 * 2);
    ushort* Wt0      = (ushort*)alloc(128 * 128 * 2);
    ushort* Wt1      = (ushort*)alloc(128 * 128 * 2);
    ushort* Wt2      = (ushort*)alloc(128 * 128 * 2);

    hipMemsetAsync(cnt, 0, (size_t)n * 4, stream);
    hipMemsetAsync(pooled, 0, (size_t)G * 128 * 4, stream);

    int eb = (E + 255) / 256;
    int nb = (n + 1023) / 1024;   // 98 for n=100000, fits k_scan2's 128 slots
    k_count<<<eb, 256, 0, stream>>>(ei, cnt, E);
    k_scan1<<<nb, 256, 0, stream>>>(cnt, row_ptr, blockSums, n);
    k_scan2<<<1, 128, 0, stream>>>(blockSums, blockOffs, nb);
    k_scan3<<<nb, 256, 0, stream>>>(row_ptr, blockOffs, n);
    k_bhead<<<1, 256, 0, stream>>>(row_ptr, bucket_head, n, E, nbuck);
    k_binA<<<(E + 4095) / 4096, 256, 0, stream>>>(ei, ea, bucket_head, tmpA, tmpE, E);
    k_binB<<<nbuck, 256, 0, stream>>>(tmpA, tmpE, row_ptr, csr_src, csr_ea, n, E);
    k_agge<<<(n + 255) / 256, 256, 0, stream>>>(csr_ea, row_ptr, cnt, agg_e, n);
    k_bounds<<<(n + 255) / 256, 256, 0, stream>>>(bat, gstart, n, G);
    k_cvt<<<(n * 32 + 255) / 256, 256, 0, stream>>>(x, xb, n * 32);
    k_cvtW<<<64, 256, 0, stream>>>(W0, Wt0);
    k_cvtW<<<64, 256, 0, stream>>>(W1, Wt1);
    k_cvtW<<<64, 256, 0, stream>>>(W2, Wt2);

    int gb = (n + 3) / 4;     // 4 waves/block, wave per node
    int mb = (n + 63) / 64;   // 64 rows per GEMM block

    k_gather_b<<<gb, 256, 0, stream>>>(xb, aggb, row_ptr, cnt, csr_src, n);
    k_gemm_mfma<<<mb, 256, 0, stream>>>(aggb, xb, agg_e, Wt0, W0, b0, n);
    k_gather_b<<<gb, 256, 0, stream>>>(xb, aggb, row_ptr, cnt, csr_src, n);
    k_gemm_mfma<<<mb, 256, 0, stream>>>(aggb, xb, agg_e, Wt1, W1, b1, n);
    k_gather_b<<<gb, 256, 0, stream>>>(xb, aggb, row_ptr, cnt, csr_src, n);
    k_gemm_mfma<<<mb, 256, 0, stream>>>(aggb, xb, agg_e, Wt2, W2, b2, n);

    k_pool2<<<G * POOL_S, 128, 0, stream>>>(xb, gstart, pooled);
    k_final<<<1, 128, 0, stream>>>(pooled, gstart, Wout, bout, out, G);
}

// Round 10
// 478.160 us; speedup vs baseline: 1.9626x; 1.1802x over previous
//
#include <hip/hip_runtime.h>

typedef __attribute__((ext_vector_type(8))) short short8;
typedef __attribute__((ext_vector_type(4))) float f32x4;
typedef __attribute__((ext_vector_type(4))) unsigned uint4v;

// ---------------- bf16 helpers ----------------
__device__ inline unsigned f2bf(float f) {
    unsigned u = __float_as_uint(f);
    u += 0x7fffu + ((u >> 16) & 1u);   // round-to-nearest-even
    return u >> 16;
}
__device__ inline float bf2f(ushort h) { return __uint_as_float(((unsigned)h) << 16); }

// ---------------- CSR build (bucketed, no global per-node atomics) ----------------

// Per-block LDS histogram over buckets (512 dst nodes per bucket) -> 196 global atomics/block.
__global__ __launch_bounds__(256) void k_bcnt(const int* __restrict__ ei, int* __restrict__ bucket_cnt, int E) {
    __shared__ int hist[256];
    int tid = threadIdx.x;
    hist[tid] = 0;
    __syncthreads();
    int e0 = blockIdx.x * 4096;
#pragma unroll
    for (int k = 0; k < 16; ++k) {
        int e = e0 + k * 256 + tid;
        if (e < E) atomicAdd(&hist[ei[E + e] >> 9], 1);
    }
    __syncthreads();
    if (hist[tid]) atomicAdd(&bucket_cnt[tid], hist[tid]);
}

// One-block scan of bucket counts -> bucket_base (nbuck+1) and bucket_head (reservation heads).
__global__ __launch_bounds__(256) void k_bscan(const int* __restrict__ bucket_cnt, int* __restrict__ bucket_base,
                                               int* __restrict__ bucket_head, int* __restrict__ row_ptr,
                                               int n, int E, int nbuck) {
    __shared__ int sdata[256];
    int tid = threadIdx.x;
    int t = (tid < nbuck) ? bucket_cnt[tid] : 0;
    int x = t;
    sdata[tid] = x; __syncthreads();
    for (int off = 1; off < 256; off <<= 1) {
        int y = (tid >= off) ? sdata[tid - off] : 0;
        __syncthreads();
        x += y; sdata[tid] = x; __syncthreads();
    }
    int excl = x - t;
    if (tid < nbuck) { bucket_base[tid] = excl; bucket_head[tid] = excl; }
    if (tid == nbuck - 1) bucket_base[nbuck] = excl + t;   // == E
    if (tid == 0) row_ptr[n] = E;
}

// Pass A: bin edges by dst bucket. tmpA = src | (dst&511)<<17 (n < 2^17),
// tmpE = edge_attr as bf16x4 (contiguous e-ordered read of ea).
__global__ __launch_bounds__(256) void k_binA(const int* __restrict__ ei, const float* __restrict__ ea,
                                              int* __restrict__ bucket_head,
                                              int* __restrict__ tmpA, uint2* __restrict__ tmpE, int E) {
    __shared__ int hist[256], base[256], fill[256];
    int tid = threadIdx.x;
    hist[tid] = 0; fill[tid] = 0;
    __syncthreads();
    int e0 = blockIdx.x * 4096;
    int d[16];
#pragma unroll
    for (int k = 0; k < 16; ++k) {
        int e = e0 + k * 256 + tid;
        d[k] = -1;
        if (e < E) { d[k] = ei[E + e]; atomicAdd(&hist[d[k] >> 9], 1); }
    }
    __syncthreads();
    if (hist[tid]) base[tid] = atomicAdd(&bucket_head[tid], hist[tid]);
    __syncthreads();
#pragma unroll
    for (int k = 0; k < 16; ++k) {
        if (d[k] >= 0) {
            int e = e0 + k * 256 + tid;
            int b = d[k] >> 9;
            int p = base[b] + atomicAdd(&fill[b], 1);
            float4 a = ((const float4*)ea)[e];
            tmpA[p] = ei[e] | ((d[k] & 511) << 17);
            tmpE[p] = make_uint2(f2bf(a.x) | (f2bf(a.y) << 16), f2bf(a.z) | (f2bf(a.w) << 16));
        }
    }
}

// Pass B: one block per bucket. Builds row_ptr (LDS hist + scan), scatters csr_src
// into the bucket's window, and accumulates agg_e in LDS fp32 (no k_agge kernel).
__global__ __launch_bounds__(256) void k_binB(const int* __restrict__ tmpA, const uint2* __restrict__ tmpE,
                                              const int* __restrict__ bucket_base, int* __restrict__ row_ptr,
                                              int* __restrict__ csr_src, float* __restrict__ agg_e, int n, int E) {
    __shared__ int lcnt[512];
    __shared__ int sscan[256];
    __shared__ float eacc[2048];
    int b = blockIdx.x;
    int lo = b << 9;
    int hi = lo + 512; if (hi > n) hi = n;
    int nn = hi - lo;
    int tid = threadIdx.x;
    lcnt[tid] = 0; lcnt[tid + 256] = 0;
#pragma unroll
    for (int i = 0; i < 8; ++i) eacc[tid + i * 256] = 0.f;
    __syncthreads();
    int jlo = bucket_base[b];
    int jhi = bucket_base[b + 1];
    // pass 1: per-node counts
    for (int j = jlo + tid; j < jhi; j += 256) {
        atomicAdd(&lcnt[tmpA[j] >> 17], 1);
    }
    __syncthreads();
    // block scan of 512 counts (2 per thread)
    int c0 = lcnt[2 * tid], c1 = lcnt[2 * tid + 1];
    int pair = c0 + c1;
    int x = pair;
    sscan[tid] = x; __syncthreads();
    for (int off = 1; off < 256; off <<= 1) {
        int y = (tid >= off) ? sscan[tid - off] : 0;
        __syncthreads();
        x += y; sscan[tid] = x; __syncthreads();
    }
    int h0 = jlo + (x - pair);
    int h1 = h0 + c0;
    __syncthreads();
    lcnt[2 * tid] = h0; lcnt[2 * tid + 1] = h1;
    if (2 * tid < nn)     row_ptr[lo + 2 * tid] = h0;
    if (2 * tid + 1 < nn) row_ptr[lo + 2 * tid + 1] = h1;
    __syncthreads();
    // pass 2: scatter + edge-attr accumulate
    for (int j = jlo + tid; j < jhi; j += 256) {
        int w = tmpA[j];
        uint2 eav = tmpE[j];
        int d = w >> 17;
        int pos = atomicAdd(&lcnt[d], 1);
        csr_src[pos] = w & 0x1FFFF;
        atomicAdd(&eacc[d * 4 + 0], bf2f((ushort)(eav.x & 0xffffu)));
        atomicAdd(&eacc[d * 4 + 1], bf2f((ushort)(eav.x >> 16)));
        atomicAdd(&eacc[d * 4 + 2], bf2f((ushort)(eav.y & 0xffffu)));
        atomicAdd(&eacc[d * 4 + 3], bf2f((ushort)(eav.y >> 16)));
    }
    __syncthreads();
    for (int i = tid; i < nn * 4; i += 256) agg_e[lo * 4 + i] = eacc[i];
}

// ---------------- one-time conversions ----------------
__global__ __launch_bounds__(256) void k_cvt(const float* __restrict__ in, ushort* __restrict__ out, int total4) {
    int i = blockIdx.x * 256 + threadIdx.x;
    if (i >= total4) return;
    float4 v = ((const float4*)in)[i];
    unsigned lo = f2bf(v.x) | (f2bf(v.y) << 16);
    unsigned hi = f2bf(v.z) | (f2bf(v.w) << 16);
    ((uint2*)out)[i] = make_uint2(lo, hi);
}

// Wt[n][k] = bf16(W[k][n]) for the 128x128 node-feature part of W
__global__ __launch_bounds__(256) void k_cvtW(const float* __restrict__ W, ushort* __restrict__ Wt) {
    int i = blockIdx.x * 256 + threadIdx.x;
    if (i >= 16384) return;
    int nn = i & 127, kk = i >> 7;
    Wt[nn * 128 + kk] = (ushort)f2bf(W[kk * 128 + nn]);
}

// ---------------- per-layer: gather aggregation ----------------
// Wave per node; 4 groups of 16 lanes; each group handles every 4th edge,
// lane loads 16B -> 4 rows in flight. (Plain loads/stores: nt hints regressed, r9.)
__global__ __launch_bounds__(256) void k_gather_b(const ushort* __restrict__ xb, ushort* __restrict__ aggb,
                                                  const int* __restrict__ row_ptr,
                                                  const int* __restrict__ csr_src, int n) {
    int wid = (blockIdx.x * 256 + threadIdx.x) >> 6;
    int lane = threadIdx.x & 63;
    if (wid >= n) return;
    int g = lane >> 4, t = lane & 15;
    const uint4v* x4 = (const uint4v*)xb;   // row = 16 uint4
    float acc[8];
    {
        uint4v v = {0u, 0u, 0u, 0u};
        if (g == 0) v = x4[(size_t)wid * 16 + t];  // self loop
        acc[0] = bf2f((ushort)(v.x & 0xffffu)); acc[1] = bf2f((ushort)(v.x >> 16));
        acc[2] = bf2f((ushort)(v.y & 0xffffu)); acc[3] = bf2f((ushort)(v.y >> 16));
        acc[4] = bf2f((ushort)(v.z & 0xffffu)); acc[5] = bf2f((ushort)(v.z >> 16));
        acc[6] = bf2f((ushort)(v.w & 0xffffu)); acc[7] = bf2f((ushort)(v.w >> 16));
    }
    int start = row_ptr[wid];
    int deg = row_ptr[wid + 1] - start;
    for (int i = g; i < deg; i += 4) {
        int s = csr_src[start + i];          // broadcast across 16 lanes
        uint4v v = x4[(size_t)s * 16 + t];
        acc[0] += bf2f((ushort)(v.x & 0xffffu)); acc[1] += bf2f((ushort)(v.x >> 16));
        acc[2] += bf2f((ushort)(v.y & 0xffffu)); acc[3] += bf2f((ushort)(v.y >> 16));
        acc[4] += bf2f((ushort)(v.z & 0xffffu)); acc[5] += bf2f((ushort)(v.z >> 16));
        acc[6] += bf2f((ushort)(v.w & 0xffffu)); acc[7] += bf2f((ushort)(v.w >> 16));
    }
#pragma unroll
    for (int j = 0; j < 8; ++j) {
        acc[j] += __shfl_xor(acc[j], 16);
        acc[j] += __shfl_xor(acc[j], 32);
    }
    if (lane < 16) {
        uint4v o;
        o.x = f2bf(acc[0]) | (f2bf(acc[1]) << 16);
        o.y = f2bf(acc[2]) | (f2bf(acc[3]) << 16);
        o.z = f2bf(acc[4]) | (f2bf(acc[5]) << 16);
        o.w = f2bf(acc[6]) | (f2bf(acc[7]) << 16);
        *(uint4v*)(aggb + (size_t)wid * 128 + lane * 8) = o;
    }
}

// ---------------- per-layer: MFMA GEMM + edge-bias + bias + relu ----------------
__global__ __launch_bounds__(256) void k_gemm_mfma(const ushort* __restrict__ aggb, ushort* __restrict__ xb_out,
                                                   const float* __restrict__ agg_e, const ushort* __restrict__ Wt,
                                                   const float* __restrict__ W, const float* __restrict__ bias, int n) {
    __shared__ float we[512];
    __shared__ float bl[128];
    int tid = threadIdx.x;
    for (int i = tid; i < 512; i += 256) we[i] = W[128 * 128 + i];
    if (tid < 128) bl[tid] = bias[tid];
    __syncthreads();

    int wave = tid >> 6, lane = tid & 63;
    int r16 = lane & 15;
    int kc = (lane >> 4) * 8;
    int row0 = blockIdx.x * 64 + wave * 16;

    int arr = row0 + r16;
    const ushort* arow = aggb + (size_t)(arr < n ? arr : (n - 1)) * 128 + kc;

    f32x4 acc[8];
#pragma unroll
    for (int t = 0; t < 8; ++t) acc[t] = (f32x4){0.f, 0.f, 0.f, 0.f};

#pragma unroll
    for (int ks = 0; ks < 4; ++ks) {
        short8 a = *(const short8*)(arow + ks * 32);
#pragma unroll
        for (int nt = 0; nt < 8; ++nt) {
            short8 b = *(const short8*)(Wt + (size_t)(nt * 16 + r16) * 128 + ks * 32 + kc);
            acc[nt] = __builtin_amdgcn_mfma_f32_16x16x32_bf16(a, b, acc[nt], 0, 0, 0);
        }
    }

#pragma unroll
    for (int r = 0; r < 4; ++r) {
        int row = row0 + (lane >> 4) * 4 + r;
        if (row >= n) continue;
        float4 e = *(const float4*)(agg_e + (size_t)row * 4);
#pragma unroll
        for (int nt = 0; nt < 8; ++nt) {
            int col = nt * 16 + r16;
            float o = acc[nt][r] + bl[col] + e.x * we[col] + e.y * we[128 + col]
                    + e.z * we[256 + col] + e.w * we[384 + col];
            o = fmaxf(o, 0.f);
            xb_out[(size_t)row * 128 + col] = (ushort)f2bf(o);
        }
    }
}

// ---------------- pooling (segmented: batch is sorted) ----------------

__global__ __launch_bounds__(256) void k_bounds(const int* __restrict__ batch, int* __restrict__ gstart,
                                                int n, int G) {
    int i = blockIdx.x * 256 + threadIdx.x;
    if (i >= n) return;
    int g = batch[i];
    if (i == 0) {
        for (int q = 0; q <= g; ++q) gstart[q] = 0;
    } else {
        int gp = batch[i - 1];
        for (int q = gp + 1; q <= g; ++q) gstart[q] = i;
    }
    if (i == n - 1) {
        for (int q = g + 1; q <= G; ++q) gstart[q] = n;
    }
}

#define POOL_S 16
__global__ __launch_bounds__(128) void k_pool2(const ushort* __restrict__ xb, const int* __restrict__ gstart,
                                               float* __restrict__ pooled) {
    int g = blockIdx.x / POOL_S;
    int s = blockIdx.x % POOL_S;
    int t = threadIdx.x;
    int lo = gstart[g], hi = gstart[g + 1];
    int len = hi - lo;
    if (len <= 0) return;
    int chunk = (len + POOL_S - 1) / POOL_S;
    int a = lo + s * chunk;
    int b = a + chunk; if (b > hi) b = hi;
    if (a >= b) return;
    float acc = 0.f;
    for (int v = a; v < b; ++v) acc += bf2f(xb[(size_t)v * 128 + t]);
    atomicAdd(&pooled[g * 128 + t], acc);
}

__global__ __launch_bounds__(128) void k_final(const float* __restrict__ pooled, const int* __restrict__ gstart,
                                               const float* __restrict__ Wout, const float* __restrict__ bout,
                                               float* __restrict__ out, int G) {
    int g = threadIdx.x;
    if (g >= G) return;
    float c = (float)(gstart[g + 1] - gstart[g]);
    if (c < 1.f) c = 1.f;
    float l0 = bout[0], l1 = bout[1], l2 = bout[2], l3 = bout[3];
    for (int k = 0; k < 128; ++k) {
        float p = pooled[g * 128 + k] / c;
        l0 += p * Wout[k * 4 + 0];
        l1 += p * Wout[k * 4 + 1];
        l2 += p * Wout[k * 4 + 2];
        l3 += p * Wout[k * 4 + 3];
    }
    float m = fmaxf(fmaxf(l0, l1), fmaxf(l2, l3));
    float s = expf(l0 - m) + expf(l1 - m) + expf(l2 - m) + expf(l3 - m);
    float ls = logf(s);
    out[g * 4 + 0] = l0 - m - ls;
    out[g * 4 + 1] = l1 - m - ls;
    out[g * 4 + 2] = l2 - m - ls;
    out[g * 4 + 3] = l3 - m - ls;
}

extern "C" void kernel_launch(void* const* d_in, const int* in_sizes, int n_in,
                              void* d_out, int out_size, void* d_ws, size_t ws_size,
                              hipStream_t stream) {
    const float* x    = (const float*)d_in[0];
    const int*   ei   = (const int*)d_in[1];
    const float* ea   = (const float*)d_in[2];
    const int*   bat  = (const int*)d_in[3];
    const float* W0   = (const float*)d_in[4];
    const float* b0   = (const float*)d_in[5];
    const float* W1   = (const float*)d_in[6];
    const float* b1   = (const float*)d_in[7];
    const float* W2   = (const float*)d_in[8];
    const float* b2   = (const float*)d_in[9];
    const float* Wout = (const float*)d_in[10];
    const float* bout = (const float*)d_in[11];
    float* out = (float*)d_out;

    int n = in_sizes[0] / 128;   // n < 2^17 assumed by tmpA packing (n = 100000 here)
    int E = in_sizes[1] / 2;
    int G = out_size / 4;
    int nbuck = (n + 511) >> 9;   // 196 for n=100000 (max 256 supported)

    char* w = (char*)d_ws;
    auto alloc = [&](size_t bytes) { char* p = w; w += (bytes + 255) & ~(size_t)255; return p; };
    int* row_ptr     = (int*)alloc((size_t)(n + 1) * 4);
    int* bucket_cnt  = (int*)alloc(1024);
    int* bucket_base = (int*)alloc(1028);
    int* bucket_head = (int*)alloc(1024);
    int* csr_src     = (int*)alloc((size_t)E * 4);
    int* tmpA        = (int*)alloc((size_t)E * 4);
    uint2* tmpE      = (uint2*)alloc((size_t)E * 8);
    float* agg_e     = (float*)alloc((size_t)n * 16);
    float* pooled    = (float*)alloc((size_t)G * 128 * 4);
    int* gstart      = (int*)alloc((size_t)(G + 4) * 4);
    ushort* xb       = (ushort*)alloc((size_t)n * 128 * 2);
    ushort* aggb     = (ushort*)alloc((size_t)n * 128 * 2);
    ushort* Wt0      = (ushort*)alloc(128 * 128 * 2);
    ushort* Wt1      = (ushort*)alloc(128 * 128 * 2);
    ushort* Wt2      = (ushort*)alloc(128 * 128 * 2);

    hipMemsetAsync(bucket_cnt, 0, 1024, stream);
    hipMemsetAsync(pooled, 0, (size_t)G * 128 * 4, stream);

    int eb16 = (E + 4095) / 4096;
    k_bcnt<<<eb16, 256, 0, stream>>>(ei, bucket_cnt, E);
    k_bscan<<<1, 256, 0, stream>>>(bucket_cnt, bucket_base, bucket_head, row_ptr, n, E, nbuck);
    k_binA<<<eb16, 256, 0, stream>>>(ei, ea, bucket_head, tmpA, tmpE, E);
    k_binB<<<nbuck, 256, 0, stream>>>(tmpA, tmpE, bucket_base, row_ptr, csr_src, agg_e, n, E);
    k_bounds<<<(n + 255) / 256, 256, 0, stream>>>(bat, gstart, n, G);
    k_cvt<<<(n * 32 + 255) / 256, 256, 0, stream>>>(x, xb, n * 32);
    k_cvtW<<<64, 256, 0, stream>>>(W0, Wt0);
    k_cvtW<<<64, 256, 0, stream>>>(W1, Wt1);
    k_cvtW<<<64, 256, 0, stream>>>(W2, Wt2);

    int gb = (n + 3) / 4;     // 4 waves/block, wave per node
    int mb = (n + 63) / 64;   // 64 rows per GEMM block

    k_gather_b<<<gb, 256, 0, stream>>>(xb, aggb, row_ptr, csr_src, n);
    k_gemm_mfma<<<mb, 256, 0, stream>>>(aggb, xb, agg_e, Wt0, W0, b0, n);
    k_gather_b<<<gb, 256, 0, stream>>>(xb, aggb, row_ptr, csr_src, n);
    k_gemm_mfma<<<mb, 256, 0, stream>>>(aggb, xb, agg_e, Wt1, W1, b1, n);
    k_gather_b<<<gb, 256, 0, stream>>>(xb, aggb, row_ptr, csr_src, n);
    k_gemm_mfma<<<mb, 256, 0, stream>>>(aggb, xb, agg_e, Wt2, W2, b2, n);

    k_pool2<<<G * POOL_S, 128, 0, stream>>>(xb, gstart, pooled);
    k_final<<<1, 128, 0, stream>>>(pooled, gstart, Wout, bout, out, G);
}

// Round 11
// 430.578 us; speedup vs baseline: 2.1795x; 1.1105x over previous
//
#include <hip/hip_runtime.h>

typedef __attribute__((ext_vector_type(8))) short short8;
typedef __attribute__((ext_vector_type(4))) float f32x4;
typedef __attribute__((ext_vector_type(4))) unsigned uint4v;

#define AST 136   // LDS tile stride in shorts: 272B = 17*16B (aligned, ~2-way banks)

// ---------------- bf16 helpers ----------------
__device__ inline unsigned f2bf(float f) {
    unsigned u = __float_as_uint(f);
    u += 0x7fffu + ((u >> 16) & 1u);   // round-to-nearest-even
    return u >> 16;
}
__device__ inline float bf2f(ushort h) { return __uint_as_float(((unsigned)h) << 16); }

// ---------------- CSR build (bucketed, no global per-node atomics) ----------------

__global__ __launch_bounds__(256) void k_bcnt(const int* __restrict__ ei, int* __restrict__ bucket_cnt, int E) {
    __shared__ int hist[256];
    int tid = threadIdx.x;
    hist[tid] = 0;
    __syncthreads();
    int e0 = blockIdx.x * 4096;
#pragma unroll
    for (int k = 0; k < 16; ++k) {
        int e = e0 + k * 256 + tid;
        if (e < E) atomicAdd(&hist[ei[E + e] >> 9], 1);
    }
    __syncthreads();
    if (hist[tid]) atomicAdd(&bucket_cnt[tid], hist[tid]);
}

__global__ __launch_bounds__(256) void k_bscan(const int* __restrict__ bucket_cnt, int* __restrict__ bucket_base,
                                               int* __restrict__ bucket_head, int* __restrict__ row_ptr,
                                               int n, int E, int nbuck) {
    __shared__ int sdata[256];
    int tid = threadIdx.x;
    int t = (tid < nbuck) ? bucket_cnt[tid] : 0;
    int x = t;
    sdata[tid] = x; __syncthreads();
    for (int off = 1; off < 256; off <<= 1) {
        int y = (tid >= off) ? sdata[tid - off] : 0;
        __syncthreads();
        x += y; sdata[tid] = x; __syncthreads();
    }
    int excl = x - t;
    if (tid < nbuck) { bucket_base[tid] = excl; bucket_head[tid] = excl; }
    if (tid == nbuck - 1) bucket_base[nbuck] = excl + t;   // == E
    if (tid == 0) row_ptr[n] = E;
}

// Pass A: bin edges by dst bucket. tmpA = src | (dst&511)<<17 (n < 2^17),
// tmpE = edge_attr as bf16x4 (contiguous e-ordered read of ea).
__global__ __launch_bounds__(256) void k_binA(const int* __restrict__ ei, const float* __restrict__ ea,
                                              int* __restrict__ bucket_head,
                                              int* __restrict__ tmpA, uint2* __restrict__ tmpE, int E) {
    __shared__ int hist[256], base[256], fill[256];
    int tid = threadIdx.x;
    hist[tid] = 0; fill[tid] = 0;
    __syncthreads();
    int e0 = blockIdx.x * 4096;
    int d[16];
#pragma unroll
    for (int k = 0; k < 16; ++k) {
        int e = e0 + k * 256 + tid;
        d[k] = -1;
        if (e < E) { d[k] = ei[E + e]; atomicAdd(&hist[d[k] >> 9], 1); }
    }
    __syncthreads();
    if (hist[tid]) base[tid] = atomicAdd(&bucket_head[tid], hist[tid]);
    __syncthreads();
#pragma unroll
    for (int k = 0; k < 16; ++k) {
        if (d[k] >= 0) {
            int e = e0 + k * 256 + tid;
            int b = d[k] >> 9;
            int p = base[b] + atomicAdd(&fill[b], 1);
            float4 a = ((const float4*)ea)[e];
            tmpA[p] = ei[e] | ((d[k] & 511) << 17);
            tmpE[p] = make_uint2(f2bf(a.x) | (f2bf(a.y) << 16), f2bf(a.z) | (f2bf(a.w) << 16));
        }
    }
}

// Pass B: one block per bucket. Builds row_ptr, scatters csr_src in a small window,
// accumulates agg_e in LDS fp32.
__global__ __launch_bounds__(256) void k_binB(const int* __restrict__ tmpA, const uint2* __restrict__ tmpE,
                                              const int* __restrict__ bucket_base, int* __restrict__ row_ptr,
                                              int* __restrict__ csr_src, float* __restrict__ agg_e, int n, int E) {
    __shared__ int lcnt[512];
    __shared__ int sscan[256];
    __shared__ float eacc[2048];
    int b = blockIdx.x;
    int lo = b << 9;
    int hi = lo + 512; if (hi > n) hi = n;
    int nn = hi - lo;
    int tid = threadIdx.x;
    lcnt[tid] = 0; lcnt[tid + 256] = 0;
#pragma unroll
    for (int i = 0; i < 8; ++i) eacc[tid + i * 256] = 0.f;
    __syncthreads();
    int jlo = bucket_base[b];
    int jhi = bucket_base[b + 1];
    for (int j = jlo + tid; j < jhi; j += 256) {
        atomicAdd(&lcnt[tmpA[j] >> 17], 1);
    }
    __syncthreads();
    int c0 = lcnt[2 * tid], c1 = lcnt[2 * tid + 1];
    int pair = c0 + c1;
    int x = pair;
    sscan[tid] = x; __syncthreads();
    for (int off = 1; off < 256; off <<= 1) {
        int y = (tid >= off) ? sscan[tid - off] : 0;
        __syncthreads();
        x += y; sscan[tid] = x; __syncthreads();
    }
    int h0 = jlo + (x - pair);
    int h1 = h0 + c0;
    __syncthreads();
    lcnt[2 * tid] = h0; lcnt[2 * tid + 1] = h1;
    if (2 * tid < nn)     row_ptr[lo + 2 * tid] = h0;
    if (2 * tid + 1 < nn) row_ptr[lo + 2 * tid + 1] = h1;
    __syncthreads();
    for (int j = jlo + tid; j < jhi; j += 256) {
        int w = tmpA[j];
        uint2 eav = tmpE[j];
        int d = w >> 17;
        int pos = atomicAdd(&lcnt[d], 1);
        csr_src[pos] = w & 0x1FFFF;
        atomicAdd(&eacc[d * 4 + 0], bf2f((ushort)(eav.x & 0xffffu)));
        atomicAdd(&eacc[d * 4 + 1], bf2f((ushort)(eav.x >> 16)));
        atomicAdd(&eacc[d * 4 + 2], bf2f((ushort)(eav.y & 0xffffu)));
        atomicAdd(&eacc[d * 4 + 3], bf2f((ushort)(eav.y >> 16)));
    }
    __syncthreads();
    for (int i = tid; i < nn * 4; i += 256) agg_e[lo * 4 + i] = eacc[i];
}

// ---------------- one-time conversions ----------------
__global__ __launch_bounds__(256) void k_cvt(const float* __restrict__ in, ushort* __restrict__ out, int total4) {
    int i = blockIdx.x * 256 + threadIdx.x;
    if (i >= total4) return;
    float4 v = ((const float4*)in)[i];
    unsigned lo = f2bf(v.x) | (f2bf(v.y) << 16);
    unsigned hi = f2bf(v.z) | (f2bf(v.w) << 16);
    ((uint2*)out)[i] = make_uint2(lo, hi);
}

__global__ __launch_bounds__(256) void k_cvtW(const float* __restrict__ W, ushort* __restrict__ Wt) {
    int i = blockIdx.x * 256 + threadIdx.x;
    if (i >= 16384) return;
    int nn = i & 127, kk = i >> 7;
    Wt[nn * 128 + kk] = (ushort)f2bf(W[kk * 128 + nn]);
}

// ---------------- fused per-layer: gather + MFMA GEMM + epilogue ----------------
// Block = 16 nodes. Phase 1: each wave gathers 4 nodes (4x 16-lane groups on the
// same node, every 4th edge, unroll x2 for MLP), shfl-reduce, A-tile to LDS.
// Phase 2: wave w computes nt = {2w, 2w+1} MFMA chains; epilogue -> LDS out-tile.
// Phase 3: coalesced 16B row stores.
__global__ __launch_bounds__(256) void k_fused(const ushort* __restrict__ xin, ushort* __restrict__ xout,
                                               const float* __restrict__ agg_e, const ushort* __restrict__ Wt,
                                               const float* __restrict__ W, const float* __restrict__ bias,
                                               const int* __restrict__ row_ptr, const int* __restrict__ csr_src,
                                               int n) {
    __shared__ ushort atile[16 * AST];
    __shared__ ushort otile[16 * AST];
    __shared__ float we[512];
    __shared__ float bl[128];
    int tid = threadIdx.x;
    int wave = tid >> 6, lane = tid & 63;
    int g = lane >> 4, t = lane & 15;
    int tile0 = blockIdx.x * 16;

    for (int i = tid; i < 512; i += 256) we[i] = W[16384 + i];
    if (tid < 128) bl[tid] = bias[tid];

    const uint4v* x4 = (const uint4v*)xin;

    // ---- phase 1: gather 4 nodes per wave ----
    for (int q = 0; q < 4; ++q) {
        int v = tile0 + wave * 4 + q;      // wave-uniform
        float acc[8] = {0.f, 0.f, 0.f, 0.f, 0.f, 0.f, 0.f, 0.f};
        if (v < n) {
            uint4v w0 = {0u, 0u, 0u, 0u};
            if (g == 0) w0 = x4[(size_t)v * 16 + t];   // self loop
            acc[0] = bf2f((ushort)(w0.x & 0xffffu)); acc[1] = bf2f((ushort)(w0.x >> 16));
            acc[2] = bf2f((ushort)(w0.y & 0xffffu)); acc[3] = bf2f((ushort)(w0.y >> 16));
            acc[4] = bf2f((ushort)(w0.z & 0xffffu)); acc[5] = bf2f((ushort)(w0.z >> 16));
            acc[6] = bf2f((ushort)(w0.w & 0xffffu)); acc[7] = bf2f((ushort)(w0.w >> 16));
            int start = row_ptr[v];
            int deg = row_ptr[v + 1] - start;
            int i = g;
            for (; i + 4 < deg; i += 8) {
                int s0 = csr_src[start + i];
                int s1 = csr_src[start + i + 4];
                uint4v v0 = x4[(size_t)s0 * 16 + t];
                uint4v v1 = x4[(size_t)s1 * 16 + t];
                acc[0] += bf2f((ushort)(v0.x & 0xffffu)); acc[1] += bf2f((ushort)(v0.x >> 16));
                acc[2] += bf2f((ushort)(v0.y & 0xffffu)); acc[3] += bf2f((ushort)(v0.y >> 16));
                acc[4] += bf2f((ushort)(v0.z & 0xffffu)); acc[5] += bf2f((ushort)(v0.z >> 16));
                acc[6] += bf2f((ushort)(v0.w & 0xffffu)); acc[7] += bf2f((ushort)(v0.w >> 16));
                acc[0] += bf2f((ushort)(v1.x & 0xffffu)); acc[1] += bf2f((ushort)(v1.x >> 16));
                acc[2] += bf2f((ushort)(v1.y & 0xffffu)); acc[3] += bf2f((ushort)(v1.y >> 16));
                acc[4] += bf2f((ushort)(v1.z & 0xffffu)); acc[5] += bf2f((ushort)(v1.z >> 16));
                acc[6] += bf2f((ushort)(v1.w & 0xffffu)); acc[7] += bf2f((ushort)(v1.w >> 16));
            }
            if (i < deg) {
                int s0 = csr_src[start + i];
                uint4v v0 = x4[(size_t)s0 * 16 + t];
                acc[0] += bf2f((ushort)(v0.x & 0xffffu)); acc[1] += bf2f((ushort)(v0.x >> 16));
                acc[2] += bf2f((ushort)(v0.y & 0xffffu)); acc[3] += bf2f((ushort)(v0.y >> 16));
                acc[4] += bf2f((ushort)(v0.z & 0xffffu)); acc[5] += bf2f((ushort)(v0.z >> 16));
                acc[6] += bf2f((ushort)(v0.w & 0xffffu)); acc[7] += bf2f((ushort)(v0.w >> 16));
            }
        }
#pragma unroll
        for (int j = 0; j < 8; ++j) {
            acc[j] += __shfl_xor(acc[j], 16);
            acc[j] += __shfl_xor(acc[j], 32);
        }
        if (lane < 16) {
            uint4v o;
            o.x = f2bf(acc[0]) | (f2bf(acc[1]) << 16);
            o.y = f2bf(acc[2]) | (f2bf(acc[3]) << 16);
            o.z = f2bf(acc[4]) | (f2bf(acc[5]) << 16);
            o.w = f2bf(acc[6]) | (f2bf(acc[7]) << 16);
            *(uint4v*)&atile[(wave * 4 + q) * AST + lane * 8] = o;
        }
    }
    __syncthreads();

    // ---- phase 2: MFMA, wave w owns nt = {2w, 2w+1} ----
    int r16 = lane & 15;
    int kc = (lane >> 4) * 8;
    f32x4 acc0 = (f32x4){0.f, 0.f, 0.f, 0.f};
    f32x4 acc1 = (f32x4){0.f, 0.f, 0.f, 0.f};
#pragma unroll
    for (int ks = 0; ks < 4; ++ks) {
        short8 a = *(const short8*)&atile[r16 * AST + ks * 32 + kc];
        short8 b0 = *(const short8*)(Wt + (size_t)(wave * 32 + r16) * 128 + ks * 32 + kc);
        short8 b1 = *(const short8*)(Wt + (size_t)(wave * 32 + 16 + r16) * 128 + ks * 32 + kc);
        acc0 = __builtin_amdgcn_mfma_f32_16x16x32_bf16(a, b0, acc0, 0, 0, 0);
        acc1 = __builtin_amdgcn_mfma_f32_16x16x32_bf16(a, b1, acc1, 0, 0, 0);
    }
#pragma unroll
    for (int r = 0; r < 4; ++r) {
        int row = (lane >> 4) * 4 + r;
        int grow = tile0 + row;
        float4 e = make_float4(0.f, 0.f, 0.f, 0.f);
        if (grow < n) e = *(const float4*)(agg_e + (size_t)grow * 4);
        int c0 = wave * 32 + r16;
        int c1 = c0 + 16;
        float o0 = acc0[r] + bl[c0] + e.x * we[c0] + e.y * we[128 + c0] + e.z * we[256 + c0] + e.w * we[384 + c0];
        float o1 = acc1[r] + bl[c1] + e.x * we[c1] + e.y * we[128 + c1] + e.z * we[256 + c1] + e.w * we[384 + c1];
        otile[row * AST + c0] = (ushort)f2bf(fmaxf(o0, 0.f));
        otile[row * AST + c1] = (ushort)f2bf(fmaxf(o1, 0.f));
    }
    __syncthreads();

    // ---- phase 3: coalesced stores (16B per thread) ----
    {
        int row = tid >> 4, c = tid & 15;
        int grow = tile0 + row;
        if (grow < n) {
            uint4v o = *(uint4v*)&otile[row * AST + c * 8];
            *(uint4v*)(xout + (size_t)grow * 128 + c * 8) = o;
        }
    }
}

// ---------------- pooling (segmented: batch is sorted) ----------------

__global__ __launch_bounds__(256) void k_bounds(const int* __restrict__ batch, int* __restrict__ gstart,
                                                int n, int G) {
    int i = blockIdx.x * 256 + threadIdx.x;
    if (i >= n) return;
    int g = batch[i];
    if (i == 0) {
        for (int q = 0; q <= g; ++q) gstart[q] = 0;
    } else {
        int gp = batch[i - 1];
        for (int q = gp + 1; q <= g; ++q) gstart[q] = i;
    }
    if (i == n - 1) {
        for (int q = g + 1; q <= G; ++q) gstart[q] = n;
    }
}

#define POOL_S 16
__global__ __launch_bounds__(128) void k_pool2(const ushort* __restrict__ xb, const int* __restrict__ gstart,
                                               float* __restrict__ pooled) {
    int g = blockIdx.x / POOL_S;
    int s = blockIdx.x % POOL_S;
    int t = threadIdx.x;
    int lo = gstart[g], hi = gstart[g + 1];
    int len = hi - lo;
    if (len <= 0) return;
    int chunk = (len + POOL_S - 1) / POOL_S;
    int a = lo + s * chunk;
    int b = a + chunk; if (b > hi) b = hi;
    if (a >= b) return;
    float acc = 0.f;
    for (int v = a; v < b; ++v) acc += bf2f(xb[(size_t)v * 128 + t]);
    atomicAdd(&pooled[g * 128 + t], acc);
}

__global__ __launch_bounds__(128) void k_final(const float* __restrict__ pooled, const int* __restrict__ gstart,
                                               const float* __restrict__ Wout, const float* __restrict__ bout,
                                               float* __restrict__ out, int G) {
    int g = threadIdx.x;
    if (g >= G) return;
    float c = (float)(gstart[g + 1] - gstart[g]);
    if (c < 1.f) c = 1.f;
    float l0 = bout[0], l1 = bout[1], l2 = bout[2], l3 = bout[3];
    for (int k = 0; k < 128; ++k) {
        float p = pooled[g * 128 + k] / c;
        l0 += p * Wout[k * 4 + 0];
        l1 += p * Wout[k * 4 + 1];
        l2 += p * Wout[k * 4 + 2];
        l3 += p * Wout[k * 4 + 3];
    }
    float m = fmaxf(fmaxf(l0, l1), fmaxf(l2, l3));
    float s = expf(l0 - m) + expf(l1 - m) + expf(l2 - m) + expf(l3 - m);
    float ls = logf(s);
    out[g * 4 + 0] = l0 - m - ls;
    out[g * 4 + 1] = l1 - m - ls;
    out[g * 4 + 2] = l2 - m - ls;
    out[g * 4 + 3] = l3 - m - ls;
}

extern "C" void kernel_launch(void* const* d_in, const int* in_sizes, int n_in,
                              void* d_out, int out_size, void* d_ws, size_t ws_size,
                              hipStream_t stream) {
    const float* x    = (const float*)d_in[0];
    const int*   ei   = (const int*)d_in[1];
    const float* ea   = (const float*)d_in[2];
    const int*   bat  = (const int*)d_in[3];
    const float* W0   = (const float*)d_in[4];
    const float* b0   = (const float*)d_in[5];
    const float* W1   = (const float*)d_in[6];
    const float* b1   = (const float*)d_in[7];
    const float* W2   = (const float*)d_in[8];
    const float* b2   = (const float*)d_in[9];
    const float* Wout = (const float*)d_in[10];
    const float* bout = (const float*)d_in[11];
    float* out = (float*)d_out;

    int n = in_sizes[0] / 128;   // n < 2^17 assumed by tmpA packing (n = 100000 here)
    int E = in_sizes[1] / 2;
    int G = out_size / 4;
    int nbuck = (n + 511) >> 9;   // 196 for n=100000 (max 256 supported)

    char* w = (char*)d_ws;
    auto alloc = [&](size_t bytes) { char* p = w; w += (bytes + 255) & ~(size_t)255; return p; };
    int* row_ptr     = (int*)alloc((size_t)(n + 1) * 4);
    int* bucket_cnt  = (int*)alloc(1024);
    int* bucket_base = (int*)alloc(1028);
    int* bucket_head = (int*)alloc(1024);
    int* csr_src     = (int*)alloc((size_t)E * 4);
    int* tmpA        = (int*)alloc((size_t)E * 4);
    uint2* tmpE      = (uint2*)alloc((size_t)E * 8);
    float* agg_e     = (float*)alloc((size_t)n * 16);
    float* pooled    = (float*)alloc((size_t)G * 128 * 4);
    int* gstart      = (int*)alloc((size_t)(G + 4) * 4);
    ushort* xb       = (ushort*)alloc((size_t)n * 128 * 2);
    ushort* yb       = (ushort*)alloc((size_t)n * 128 * 2);
    ushort* Wt0      = (ushort*)alloc(128 * 128 * 2);
    ushort* Wt1      = (ushort*)alloc(128 * 128 * 2);
    ushort* Wt2      = (ushort*)alloc(128 * 128 * 2);

    hipMemsetAsync(bucket_cnt, 0, 1024, stream);
    hipMemsetAsync(pooled, 0, (size_t)G * 128 * 4, stream);

    int eb16 = (E + 4095) / 4096;
    k_bcnt<<<eb16, 256, 0, stream>>>(ei, bucket_cnt, E);
    k_bscan<<<1, 256, 0, stream>>>(bucket_cnt, bucket_base, bucket_head, row_ptr, n, E, nbuck);
    k_binA<<<eb16, 256, 0, stream>>>(ei, ea, bucket_head, tmpA, tmpE, E);
    k_binB<<<nbuck, 256, 0, stream>>>(tmpA, tmpE, bucket_base, row_ptr, csr_src, agg_e, n, E);
    k_bounds<<<(n + 255) / 256, 256, 0, stream>>>(bat, gstart, n, G);
    k_cvt<<<(n * 32 + 255) / 256, 256, 0, stream>>>(x, xb, n * 32);
    k_cvtW<<<64, 256, 0, stream>>>(W0, Wt0);
    k_cvtW<<<64, 256, 0, stream>>>(W1, Wt1);
    k_cvtW<<<64, 256, 0, stream>>>(W2, Wt2);

    int fb = (n + 15) / 16;   // fused blocks: 16 nodes per block

    k_fused<<<fb, 256, 0, stream>>>(xb, yb, agg_e, Wt0, W0, b0, row_ptr, csr_src, n);
    k_fused<<<fb, 256, 0, stream>>>(yb, xb, agg_e, Wt1, W1, b1, row_ptr, csr_src, n);
    k_fused<<<fb, 256, 0, stream>>>(xb, yb, agg_e, Wt2, W2, b2, row_ptr, csr_src, n);

    k_pool2<<<G * POOL_S, 128, 0, stream>>>(yb, gstart, pooled);
    k_final<<<1, 128, 0, stream>>>(pooled, gstart, Wout, bout, out, G);
}